// Round 5
// baseline (297.885 us; speedup 1.0000x reference)
//
#include <hip/hip_runtime.h>

// GraphSAGE 2-layer forward.
// Round 5: one-wave 64x64 GEMM blocks (no barriers, single 16KB LDS buffer,
// register-frag prefetch pipeline) -- attacks the measured 85%-idle /
// barrier-lockstep stall. Layer 1 also reordered via linearity:
// y = x@[W1l|W1r], then fused gather: h = relu(mean(y1[nbr]) + y2 + b1).

#define N_NODES 50000
#define N_EDGES 800000

typedef unsigned short ushort_t;
typedef __attribute__((ext_vector_type(8))) short short8v;   // 8 bf16
typedef __attribute__((ext_vector_type(4))) float f32x4;

__device__ __forceinline__ float b2f(ushort_t u) {
    union { unsigned int i; float f; } v; v.i = (unsigned int)u << 16; return v.f;
}
__device__ __forceinline__ ushort_t f2b(float f) {
    union { float f; unsigned int i; } v; v.f = f;
    unsigned int r = 0x7fffu + ((v.i >> 16) & 1u);   // RNE
    return (ushort_t)((v.i + r) >> 16);
}

__device__ __forceinline__ void gload_lds16(const void* gsrc, void* ldsdst) {
    auto* l3 = reinterpret_cast<__attribute__((address_space(3))) unsigned int*>(
        reinterpret_cast<uintptr_t>(ldsdst));
    __builtin_amdgcn_global_load_lds(
        reinterpret_cast<const unsigned int*>(gsrc), l3, 16, 0, 0);
}

// ---------------- CSR build ----------------
__global__ __launch_bounds__(256) void edge_hist(
    const int* __restrict__ ei, int* __restrict__ deg, int E)
{
    int e = blockIdx.x * blockDim.x + threadIdx.x;
    if (e < E) atomicAdd(&deg[ei[E + e]], 1);
}

#define SCAN_B 256
__global__ __launch_bounds__(256) void scan1(
    const int* __restrict__ deg, int* __restrict__ excl,
    int* __restrict__ bsum, int N)
{
    __shared__ int s[SCAN_B];
    int t = threadIdx.x;
    int i = blockIdx.x * SCAN_B + t;
    int v = (i < N) ? deg[i] : 0;
    s[t] = v;
    __syncthreads();
    for (int off = 1; off < SCAN_B; off <<= 1) {
        int add = (t >= off) ? s[t - off] : 0;
        __syncthreads();
        s[t] += add;
        __syncthreads();
    }
    if (i < N) excl[i] = s[t] - v;
    if (t == SCAN_B - 1) bsum[blockIdx.x] = s[t];
}

__global__ __launch_bounds__(256) void scan2(int* __restrict__ bsum, int nb)
{
    __shared__ int s[SCAN_B];
    int t = threadIdx.x;
    int v = (t < nb) ? bsum[t] : 0;
    s[t] = v;
    __syncthreads();
    for (int off = 1; off < SCAN_B; off <<= 1) {
        int add = (t >= off) ? s[t - off] : 0;
        __syncthreads();
        s[t] += add;
        __syncthreads();
    }
    if (t < nb) bsum[t] = s[t] - v;
}

__global__ __launch_bounds__(256) void scan3(
    int* __restrict__ rp, int* __restrict__ cursor,
    const int* __restrict__ bsum, int N, int E)
{
    int i = blockIdx.x * SCAN_B + threadIdx.x;
    if (i < N) {
        int v = rp[i] + bsum[blockIdx.x];
        rp[i] = v;
        cursor[i] = v;
    }
    if (i == 0) rp[N] = E;
}

__global__ __launch_bounds__(256) void edge_fill(
    const int* __restrict__ ei, int* __restrict__ cursor,
    int* __restrict__ col, int E)
{
    int e = blockIdx.x * blockDim.x + threadIdx.x;
    if (e >= E) return;
    int d = ei[E + e], s = ei[e];
    int pos = atomicAdd(&cursor[d], 1);
    col[pos] = s;
}

// ---------------- casts ----------------
__global__ __launch_bounds__(256) void cast_f32_bf16(
    const float* __restrict__ in, ushort_t* __restrict__ out, int n4)
{
    int i = blockIdx.x * blockDim.x + threadIdx.x;
    int stride = gridDim.x * blockDim.x;
    for (; i < n4; i += stride) {
        float4 v = ((const float4*)in)[i];
        ushort4 o;
        o.x = f2b(v.x); o.y = f2b(v.y); o.z = f2b(v.z); o.w = f2b(v.w);
        ((ushort4*)out)[i] = o;
    }
}

// Bt1[512][256] = [W1l|W1r]^T ; Bt2[256][256] = [W2l|W2r]^T  (bf16, [n][k])
__global__ __launch_bounds__(256) void build_bt(
    const float* __restrict__ W1l, const float* __restrict__ W1r,
    const float* __restrict__ W2l, const float* __restrict__ W2r,
    ushort_t* __restrict__ Bt1, ushort_t* __restrict__ Bt2)
{
    int i = blockIdx.x * 256 + threadIdx.x;
    if (i < 512 * 256) {
        int n = i >> 8, k = i & 255;
        float v = (n < 256) ? W1l[k * 256 + n] : W1r[k * 256 + (n - 256)];
        Bt1[i] = f2b(v);
    }
    int j = i - 512 * 256;
    if (j >= 0 && j < 256 * 256) {
        int n = j >> 8, k = j & 255;
        float v = (n < 128) ? W2l[k * 128 + n] : W2r[k * 128 + (n - 128)];
        Bt2[j] = f2b(v);
    }
}

// ---------------- one-wave 64x64 bf16 MFMA GEMM, K=256 ----------------
// No barriers: 1 wave/block, wave-synchronous LDS, single 16 KB buffer,
// register-fragment prefetch: vmcnt(0) -> ds_read 16 frags -> lgkmcnt(0)
// -> restage buffer for kt+1 -> 32 MFMA overlap the in-flight loads.
// MODE 0: C[row][c] bf16 to outb (ld 512), bias added for c>=256 (b1).
// MODE 1: c<128 -> outb bf16 (ld 128); c>=128 -> outf f32 (ld 128) + bias.
template<int MODE>
__global__ __launch_bounds__(64) void gemm64(
    const ushort_t* __restrict__ A, const ushort_t* __restrict__ Bt,
    const float* __restrict__ bias,
    ushort_t* __restrict__ outb, float* __restrict__ outf, int M)
{
    __shared__ ushort_t As[64][64];   // 8 KB, row = 128 B
    __shared__ ushort_t Bs[64][64];   // 8 KB

    const int lane = threadIdx.x;
    const int row0 = blockIdx.x * 64;
    const int col0 = blockIdx.y * 64;

    auto stage = [&](int kt) {
        const int kA = kt * 64;
        #pragma unroll
        for (int i = 0; i < 8; ++i) {
            int o    = (i * 64 + lane) * 16;          // linear dest byte
            int row  = o >> 7;
            int kb   = (o & 127) ^ ((row & 7) << 4);  // inverse-swizzled src
            int grow = row0 + row; if (grow >= M) grow = M - 1;
            gload_lds16(A + (size_t)grow * 256 + kA + (kb >> 1),
                        (char*)&As[0][0] + i * 1024);
        }
        #pragma unroll
        for (int i = 0; i < 8; ++i) {
            int o   = (i * 64 + lane) * 16;
            int row = o >> 7;
            int kb  = (o & 127) ^ ((row & 7) << 4);
            gload_lds16(Bt + (size_t)(col0 + row) * 256 + kA + (kb >> 1),
                        (char*)&Bs[0][0] + i * 1024);
        }
    };

    f32x4 acc[4][4] = {};
    stage(0);

    #pragma unroll
    for (int kt = 0; kt < 4; ++kt) {
        asm volatile("s_waitcnt vmcnt(0)" ::: "memory");   // tile kt in LDS
        __builtin_amdgcn_sched_barrier(0);

        short8v af[2][4], bg[2][4];
        #pragma unroll
        for (int ks = 0; ks < 2; ++ks) {
            #pragma unroll
            for (int mi = 0; mi < 4; ++mi) {
                int row = (mi << 4) + (lane & 15);
                int kb  = ((ks << 6) + ((lane >> 4) << 4)) ^ ((row & 7) << 4);
                af[ks][mi] = *(const short8v*)((const char*)&As[0][0] + row * 128 + kb);
                bg[ks][mi] = *(const short8v*)((const char*)&Bs[0][0] + row * 128 + kb);
            }
        }
        asm volatile("s_waitcnt lgkmcnt(0)" ::: "memory"); // frags in regs
        __builtin_amdgcn_sched_barrier(0);
        if (kt < 3) stage(kt + 1);                          // overwrite is safe now
        __builtin_amdgcn_sched_barrier(0);

        #pragma unroll
        for (int ks = 0; ks < 2; ++ks)
            #pragma unroll
            for (int mi = 0; mi < 4; ++mi)
                #pragma unroll
                for (int nj = 0; nj < 4; ++nj)
                    acc[mi][nj] = __builtin_amdgcn_mfma_f32_16x16x32_bf16(
                        af[ks][mi], bg[ks][nj], acc[mi][nj], 0, 0, 0);
    }

    // epilogue: C/D layout col=lane&15, row=(lane>>4)*4+r
    #pragma unroll
    for (int mi = 0; mi < 4; ++mi) {
        #pragma unroll
        for (int nj = 0; nj < 4; ++nj) {
            int c = col0 + (nj << 4) + (lane & 15);
            #pragma unroll
            for (int r = 0; r < 4; ++r) {
                int row = row0 + (mi << 4) + ((lane >> 4) << 2) + r;
                if (row >= M) continue;
                float v = acc[mi][nj][r];
                if (MODE == 0) {
                    if (c >= 256) v += bias[c - 256];      // fold b1 into y2
                    outb[(size_t)row * 512 + c] = f2b(v);
                } else {
                    if (c < 128) {
                        outb[(size_t)row * 128 + c] = f2b(v);
                    } else {
                        outf[(size_t)row * 128 + (c - 128)] = v + bias[c - 128];
                    }
                }
            }
        }
    }
}

// ---------------- fused gather 1: h = relu(mean(y1[nbr]) + y2 + b1) -------
// y is [N][512] bf16: y1 = cols 0..255 (x@W1l), y2 = cols 256..511 (x@W1r+b1)
__global__ __launch_bounds__(256) void fused_gather1(
    const ushort_t* __restrict__ y, const int* __restrict__ rp,
    const int* __restrict__ col, ushort_t* __restrict__ h, int N)
{
    int gid  = blockIdx.x * blockDim.x + threadIdx.x;
    int node = gid >> 6;
    int lane = gid & 63;
    if (node >= N) return;
    int rs = rp[node], re = rp[node + 1];

    float acc[4] = {0.f, 0.f, 0.f, 0.f};
    for (int base = rs; base < re; base += 64) {
        int m = re - base; if (m > 64) m = 64;
        int c = (lane < m) ? col[base + lane] : 0;
        int j = 0;
        for (; j + 4 <= m; j += 4) {
            int s0 = __shfl(c, j), s1 = __shfl(c, j + 1);
            int s2 = __shfl(c, j + 2), s3 = __shfl(c, j + 3);
            ushort4 t0 = *(const ushort4*)(y + (size_t)s0 * 512 + lane * 4);
            ushort4 t1 = *(const ushort4*)(y + (size_t)s1 * 512 + lane * 4);
            ushort4 t2 = *(const ushort4*)(y + (size_t)s2 * 512 + lane * 4);
            ushort4 t3 = *(const ushort4*)(y + (size_t)s3 * 512 + lane * 4);
            acc[0] += b2f(t0.x) + b2f(t1.x) + b2f(t2.x) + b2f(t3.x);
            acc[1] += b2f(t0.y) + b2f(t1.y) + b2f(t2.y) + b2f(t3.y);
            acc[2] += b2f(t0.z) + b2f(t1.z) + b2f(t2.z) + b2f(t3.z);
            acc[3] += b2f(t0.w) + b2f(t1.w) + b2f(t2.w) + b2f(t3.w);
        }
        for (; j < m; ++j) {
            int src = __shfl(c, j);
            ushort4 t = *(const ushort4*)(y + (size_t)src * 512 + lane * 4);
            acc[0] += b2f(t.x); acc[1] += b2f(t.y);
            acc[2] += b2f(t.z); acc[3] += b2f(t.w);
        }
    }

    float s = 1.0f / (float)max(re - rs, 1);
    ushort4 t2 = *(const ushort4*)(y + (size_t)node * 512 + 256 + lane * 4);
    ushort4 o;
    o.x = f2b(fmaxf(acc[0] * s + b2f(t2.x), 0.f));
    o.y = f2b(fmaxf(acc[1] * s + b2f(t2.y), 0.f));
    o.z = f2b(fmaxf(acc[2] * s + b2f(t2.z), 0.f));
    o.w = f2b(fmaxf(acc[3] * s + b2f(t2.w), 0.f));
    *(ushort4*)(h + (size_t)node * 256 + lane * 4) = o;
}

// ---------------- fused gather 2: out += mean(zb[nbr]) --------------------
__global__ __launch_bounds__(256) void fused_gather2(
    const ushort_t* __restrict__ zb, const int* __restrict__ rp,
    const int* __restrict__ col, float* __restrict__ out, int N)
{
    int gid  = blockIdx.x * blockDim.x + threadIdx.x;
    int node = gid >> 6;
    int lane = gid & 63;
    if (node >= N) return;
    int rs = rp[node], re = rp[node + 1];

    float acc[2] = {0.f, 0.f};
    for (int base = rs; base < re; base += 64) {
        int m = re - base; if (m > 64) m = 64;
        int c = (lane < m) ? col[base + lane] : 0;
        int j = 0;
        for (; j + 4 <= m; j += 4) {
            int s0 = __shfl(c, j), s1 = __shfl(c, j + 1);
            int s2 = __shfl(c, j + 2), s3 = __shfl(c, j + 3);
            ushort2 t0 = *(const ushort2*)(zb + (size_t)s0 * 128 + lane * 2);
            ushort2 t1 = *(const ushort2*)(zb + (size_t)s1 * 128 + lane * 2);
            ushort2 t2 = *(const ushort2*)(zb + (size_t)s2 * 128 + lane * 2);
            ushort2 t3 = *(const ushort2*)(zb + (size_t)s3 * 128 + lane * 2);
            acc[0] += b2f(t0.x) + b2f(t1.x) + b2f(t2.x) + b2f(t3.x);
            acc[1] += b2f(t0.y) + b2f(t1.y) + b2f(t2.y) + b2f(t3.y);
        }
        for (; j < m; ++j) {
            int src = __shfl(c, j);
            ushort2 t = *(const ushort2*)(zb + (size_t)src * 128 + lane * 2);
            acc[0] += b2f(t.x); acc[1] += b2f(t.y);
        }
    }

    float s = 1.0f / (float)max(re - rs, 1);
    float2 p = *(float2*)(out + (size_t)node * 128 + lane * 2);
    p.x += acc[0] * s; p.y += acc[1] * s;
    *(float2*)(out + (size_t)node * 128 + lane * 2) = p;
}

extern "C" void kernel_launch(void* const* d_in, const int* in_sizes, int n_in,
                              void* d_out, int out_size, void* d_ws, size_t ws_size,
                              hipStream_t stream)
{
    const float* x   = (const float*)d_in[0];
    const int*   ei  = (const int*)d_in[1];
    const float* W1l = (const float*)d_in[2];
    const float* b1  = (const float*)d_in[3];
    const float* W1r = (const float*)d_in[4];
    const float* W2l = (const float*)d_in[5];
    const float* b2  = (const float*)d_in[6];
    const float* W2r = (const float*)d_in[7];
    float* out = (float*)d_out;

    const int N = N_NODES, E = N_EDGES;

    // workspace layout (256 B aligned)
    const size_t off_deg  = 0;                               // int[50000]
    const size_t off_rp   = 204800;                          // int[50001]
    const size_t off_cur  = 409600;                          // int[50000]
    const size_t off_bsum = 614400;                          // int[256]
    const size_t off_col  = 615424;                          // int[800000]
    const size_t off_xb   = 3815424;                         // bf16 [N][256]; h overlays after GEMM_A
    const size_t off_y    = off_xb + (size_t)N * 256 * 2;    // bf16 [N][512]; zb overlays after gather1
    const size_t off_bt1  = off_y  + (size_t)N * 512 * 2;
    const size_t off_bt2  = off_bt1 + 512 * 256 * 2;
    const size_t required = off_bt2 + 256 * 256 * 2;         // ~81 MB
    if (ws_size < required) return;

    char* ws = (char*)d_ws;
    int*      deg    = (int*)(ws + off_deg);
    int*      rp     = (int*)(ws + off_rp);
    int*      cursor = (int*)(ws + off_cur);
    int*      bsum   = (int*)(ws + off_bsum);
    int*      col    = (int*)(ws + off_col);
    ushort_t* xb     = (ushort_t*)(ws + off_xb);
    ushort_t* h      = (ushort_t*)(ws + off_xb);   // overlays xb (dead after GEMM_A)
    ushort_t* y      = (ushort_t*)(ws + off_y);
    ushort_t* zb     = (ushort_t*)(ws + off_y);    // overlays y (dead after gather1)
    ushort_t* Bt1    = (ushort_t*)(ws + off_bt1);
    ushort_t* Bt2    = (ushort_t*)(ws + off_bt2);

    const int eb = (E + 255) / 256;
    const int nb = (N + SCAN_B - 1) / SCAN_B;
    const int mt = (N + 63) / 64;     // 782 one-wave M-tiles

    // ---- CSR build ----
    hipMemsetAsync(deg, 0, (size_t)N * 4, stream);
    hipLaunchKernelGGL(edge_hist, dim3(eb), dim3(256), 0, stream, ei, deg, E);
    hipLaunchKernelGGL(scan1, dim3(nb), dim3(SCAN_B), 0, stream, deg, rp, bsum, N);
    hipLaunchKernelGGL(scan2, dim3(1), dim3(SCAN_B), 0, stream, bsum, nb);
    hipLaunchKernelGGL(scan3, dim3(nb), dim3(SCAN_B), 0, stream, rp, cursor, bsum, N, E);
    hipLaunchKernelGGL(edge_fill, dim3(eb), dim3(256), 0, stream, ei, cursor, col, E);

    // ---- casts ----
    hipLaunchKernelGGL(cast_f32_bf16, dim3(2048), dim3(256), 0, stream,
                       x, xb, N * 256 / 4);
    hipLaunchKernelGGL(build_bt, dim3(768), dim3(256), 0, stream,
                       W1l, W1r, W2l, W2r, Bt1, Bt2);

    // ---- layer 1: y = xb@[W1l|W1r] (+b1 on y2); h = relu(mean(y1)+y2) ----
    hipLaunchKernelGGL((gemm64<0>), dim3(mt, 8), dim3(64), 0, stream,
                       xb, Bt1, b1, y, (float*)nullptr, N);
    hipLaunchKernelGGL(fused_gather1, dim3((N + 3) / 4), dim3(256), 0, stream,
                       y, rp, col, h, N);

    // ---- layer 2: [zb|out] = h@[W2l|W2r] (+b2 on out); out += mean(zb) ----
    hipLaunchKernelGGL((gemm64<1>), dim3(mt, 4), dim3(64), 0, stream,
                       h, Bt2, b2, zb, out, N);
    hipLaunchKernelGGL(fused_gather2, dim3((N + 3) / 4), dim3(256), 0, stream,
                       zb, rp, col, out, N);
}

// Round 6
// 279.858 us; speedup vs baseline: 1.0644x; 1.0644x over previous
//
#include <hip/hip_runtime.h>

// GraphSAGE 2-layer forward.
// Round 6: GEMM occupancy fix -- BK=32 halves LDS (32KB dbuf) and
// __launch_bounds__(256,4) caps VGPR<=128 => ~16 waves/CU (vs <=8 in all
// prior rounds). Grid flipped to (col,row) so co-resident blocks share the
// A row-slab in L2 (round-5 FETCH was 2x A). Counted vmcnt(4), raw
// barriers, setprio around MFMA. Gathers unrolled 8-wide.

#define N_NODES 50000
#define N_EDGES 800000

typedef unsigned short ushort_t;
typedef __attribute__((ext_vector_type(8))) short short8v;   // 8 bf16
typedef __attribute__((ext_vector_type(4))) float f32x4;

__device__ __forceinline__ float b2f(ushort_t u) {
    union { unsigned int i; float f; } v; v.i = (unsigned int)u << 16; return v.f;
}
__device__ __forceinline__ ushort_t f2b(float f) {
    union { float f; unsigned int i; } v; v.f = f;
    unsigned int r = 0x7fffu + ((v.i >> 16) & 1u);   // RNE
    return (ushort_t)((v.i + r) >> 16);
}

__device__ __forceinline__ void gload_lds16(const void* gsrc, void* ldsdst) {
    auto* l3 = reinterpret_cast<__attribute__((address_space(3))) unsigned int*>(
        reinterpret_cast<uintptr_t>(ldsdst));
    __builtin_amdgcn_global_load_lds(
        reinterpret_cast<const unsigned int*>(gsrc), l3, 16, 0, 0);
}

// ---------------- CSR build ----------------
__global__ __launch_bounds__(256) void edge_hist(
    const int* __restrict__ ei, int* __restrict__ deg, int E)
{
    int e = blockIdx.x * blockDim.x + threadIdx.x;
    if (e < E) atomicAdd(&deg[ei[E + e]], 1);
}

#define SCAN_B 256
__global__ __launch_bounds__(256) void scan1(
    const int* __restrict__ deg, int* __restrict__ excl,
    int* __restrict__ bsum, int N)
{
    __shared__ int s[SCAN_B];
    int t = threadIdx.x;
    int i = blockIdx.x * SCAN_B + t;
    int v = (i < N) ? deg[i] : 0;
    s[t] = v;
    __syncthreads();
    for (int off = 1; off < SCAN_B; off <<= 1) {
        int add = (t >= off) ? s[t - off] : 0;
        __syncthreads();
        s[t] += add;
        __syncthreads();
    }
    if (i < N) excl[i] = s[t] - v;
    if (t == SCAN_B - 1) bsum[blockIdx.x] = s[t];
}

__global__ __launch_bounds__(256) void scan2(int* __restrict__ bsum, int nb)
{
    __shared__ int s[SCAN_B];
    int t = threadIdx.x;
    int v = (t < nb) ? bsum[t] : 0;
    s[t] = v;
    __syncthreads();
    for (int off = 1; off < SCAN_B; off <<= 1) {
        int add = (t >= off) ? s[t - off] : 0;
        __syncthreads();
        s[t] += add;
        __syncthreads();
    }
    if (t < nb) bsum[t] = s[t] - v;
}

__global__ __launch_bounds__(256) void scan3(
    int* __restrict__ rp, int* __restrict__ cursor,
    const int* __restrict__ bsum, int N, int E)
{
    int i = blockIdx.x * SCAN_B + threadIdx.x;
    if (i < N) {
        int v = rp[i] + bsum[blockIdx.x];
        rp[i] = v;
        cursor[i] = v;
    }
    if (i == 0) rp[N] = E;
}

__global__ __launch_bounds__(256) void edge_fill(
    const int* __restrict__ ei, int* __restrict__ cursor,
    int* __restrict__ col, int E)
{
    int e = blockIdx.x * blockDim.x + threadIdx.x;
    if (e >= E) return;
    int d = ei[E + e], s = ei[e];
    int pos = atomicAdd(&cursor[d], 1);
    col[pos] = s;
}

// ---------------- casts ----------------
__global__ __launch_bounds__(256) void cast_f32_bf16(
    const float* __restrict__ in, ushort_t* __restrict__ out, int n4)
{
    int i = blockIdx.x * blockDim.x + threadIdx.x;
    int stride = gridDim.x * blockDim.x;
    for (; i < n4; i += stride) {
        float4 v = ((const float4*)in)[i];
        ushort4 o;
        o.x = f2b(v.x); o.y = f2b(v.y); o.z = f2b(v.z); o.w = f2b(v.w);
        ((ushort4*)out)[i] = o;
    }
}

// Bt1[512][256] = [W1l|W1r]^T ; Bt2[256][256] = [W2l|W2r]^T  (bf16, [n][k])
__global__ __launch_bounds__(256) void build_bt(
    const float* __restrict__ W1l, const float* __restrict__ W1r,
    const float* __restrict__ W2l, const float* __restrict__ W2r,
    ushort_t* __restrict__ Bt1, ushort_t* __restrict__ Bt2)
{
    int i = blockIdx.x * 256 + threadIdx.x;
    if (i < 512 * 256) {
        int n = i >> 8, k = i & 255;
        float v = (n < 256) ? W1l[k * 256 + n] : W1r[k * 256 + (n - 256)];
        Bt1[i] = f2b(v);
    }
    int j = i - 512 * 256;
    if (j >= 0 && j < 256 * 256) {
        int n = j >> 8, k = j & 255;
        float v = (n < 128) ? W2l[k * 128 + n] : W2r[k * 128 + (n - 128)];
        Bt2[j] = f2b(v);
    }
}

// ---------------- bf16 MFMA GEMM: 128x128 tile, BK=32, dbuf, 4 waves ------
// K fixed = 256 (8 K-iters). LDS 32 KB -> ~4 blocks/CU with VGPR<=128.
// grid = (ncolTiles, nrowTiles): consecutive blocks share the A row-slab.
// MODE 0: C bf16 -> outb (ld 512), +bias for c>=256 (b1 folded into y2).
// MODE 1: c<128 -> outb bf16 (ld 128); c>=128 -> outf f32 (ld 128) + bias.
template<int MODE>
__global__ __launch_bounds__(256, 4) void gemm_mfma(
    const ushort_t* __restrict__ A, const ushort_t* __restrict__ Bt,
    const float* __restrict__ bias,
    ushort_t* __restrict__ outb, float* __restrict__ outf, int M)
{
    __shared__ ushort_t As[2][128][32];   // 2 x 8 KB, row = 64 B
    __shared__ ushort_t Bs[2][128][32];

    const int t    = threadIdx.x;
    const int lane = t & 63;
    const int w    = t >> 6;
    const int wr   = w >> 1, wc = w & 1;
    const int col0 = blockIdx.x * 128;    // col fastest -> A-slab L2 reuse
    const int row0 = blockIdx.y * 128;

    f32x4 acc[4][4] = {};

    // stage one 32-wide K-slice of A and B into buf (4 gload instrs/wave)
    auto stage = [&](int kt, int buf) {
        const int kA = kt * 32;
        #pragma unroll
        for (int i = 0; i < 2; ++i) {
            int idx  = i * 256 + t;                    // 0..511
            int row  = idx >> 2;                       // 4 x 16B chunks / row
            int kb   = ((idx & 3) * 16) ^ ((row & 3) << 4);  // inv-swizzled src
            int grow = row0 + row; if (grow >= M) grow = M - 1;
            gload_lds16(A + (size_t)grow * 256 + kA + (kb >> 1),
                        (char*)&As[buf][0][0] + i * 4096 + w * 1024);
        }
        #pragma unroll
        for (int i = 0; i < 2; ++i) {
            int idx = i * 256 + t;
            int row = idx >> 2;
            int kb  = ((idx & 3) * 16) ^ ((row & 3) << 4);
            gload_lds16(Bt + (size_t)(col0 + row) * 256 + kA + (kb >> 1),
                        (char*)&Bs[buf][0][0] + i * 4096 + w * 1024);
        }
    };

    stage(0, 0);
    #pragma unroll
    for (int kt = 0; kt < 8; ++kt) {
        const int buf = kt & 1;
        if (kt < 7) {
            stage(kt + 1, buf ^ 1);                    // prefetch next slice
            asm volatile("s_waitcnt vmcnt(4)");        // wait CURRENT only
        } else {
            asm volatile("s_waitcnt vmcnt(0)");
        }
        __builtin_amdgcn_sched_barrier(0);
        __builtin_amdgcn_s_barrier();                  // tile valid for all
        __builtin_amdgcn_sched_barrier(0);

        short8v af[4], bg[4];
        #pragma unroll
        for (int mi = 0; mi < 4; ++mi) {
            int r = (wr << 6) + (mi << 4) + (lane & 15);
            int b = (((lane >> 4) << 4)) ^ ((r & 3) << 4);
            af[mi] = *(const short8v*)((const char*)&As[buf][0][0] + r * 64 + b);
        }
        #pragma unroll
        for (int nj = 0; nj < 4; ++nj) {
            int r = (wc << 6) + (nj << 4) + (lane & 15);
            int b = (((lane >> 4) << 4)) ^ ((r & 3) << 4);
            bg[nj] = *(const short8v*)((const char*)&Bs[buf][0][0] + r * 64 + b);
        }

        __builtin_amdgcn_s_setprio(1);
        #pragma unroll
        for (int mi = 0; mi < 4; ++mi)
            #pragma unroll
            for (int nj = 0; nj < 4; ++nj)
                acc[mi][nj] = __builtin_amdgcn_mfma_f32_16x16x32_bf16(
                    af[mi], bg[nj], acc[mi][nj], 0, 0, 0);
        __builtin_amdgcn_s_setprio(0);

        __builtin_amdgcn_sched_barrier(0);
        __builtin_amdgcn_s_barrier();                  // release buf for kt+2
        __builtin_amdgcn_sched_barrier(0);
    }

    // epilogue: C/D layout col=lane&15, row=(lane>>4)*4+r
    #pragma unroll
    for (int mi = 0; mi < 4; ++mi) {
        #pragma unroll
        for (int nj = 0; nj < 4; ++nj) {
            int c = col0 + (wc << 6) + (nj << 4) + (lane & 15);
            #pragma unroll
            for (int r = 0; r < 4; ++r) {
                int row = row0 + (wr << 6) + (mi << 4) + ((lane >> 4) << 2) + r;
                if (row >= M) continue;
                float v = acc[mi][nj][r];
                if (MODE == 0) {
                    if (c >= 256) v += bias[c - 256];
                    outb[(size_t)row * 512 + c] = f2b(v);
                } else {
                    if (c < 128) {
                        outb[(size_t)row * 128 + c] = f2b(v);
                    } else {
                        outf[(size_t)row * 128 + (c - 128)] = v + bias[c - 128];
                    }
                }
            }
        }
    }
}

// ---------------- fused gather 1: h = relu(mean(y1[nbr]) + y2) ------------
// y is [N][512] bf16: y1 = cols 0..255 (x@W1l), y2 = cols 256..511 (x@W1r+b1)
__global__ __launch_bounds__(256) void fused_gather1(
    const ushort_t* __restrict__ y, const int* __restrict__ rp,
    const int* __restrict__ col, ushort_t* __restrict__ h, int N)
{
    int gid  = blockIdx.x * blockDim.x + threadIdx.x;
    int node = gid >> 6;
    int lane = gid & 63;
    if (node >= N) return;
    int rs = rp[node], re = rp[node + 1];

    float acc[4] = {0.f, 0.f, 0.f, 0.f};
    for (int base = rs; base < re; base += 64) {
        int m = re - base; if (m > 64) m = 64;
        int c = (lane < m) ? col[base + lane] : 0;
        int j = 0;
        for (; j + 8 <= m; j += 8) {     // 8 loads in flight
            ushort4 tv[8];
            #pragma unroll
            for (int q = 0; q < 8; ++q) {
                int sq = __shfl(c, j + q);
                tv[q] = *(const ushort4*)(y + (size_t)sq * 512 + lane * 4);
            }
            #pragma unroll
            for (int q = 0; q < 8; ++q) {
                acc[0] += b2f(tv[q].x); acc[1] += b2f(tv[q].y);
                acc[2] += b2f(tv[q].z); acc[3] += b2f(tv[q].w);
            }
        }
        for (; j < m; ++j) {
            int src = __shfl(c, j);
            ushort4 tq = *(const ushort4*)(y + (size_t)src * 512 + lane * 4);
            acc[0] += b2f(tq.x); acc[1] += b2f(tq.y);
            acc[2] += b2f(tq.z); acc[3] += b2f(tq.w);
        }
    }

    float s = 1.0f / (float)max(re - rs, 1);
    ushort4 t2 = *(const ushort4*)(y + (size_t)node * 512 + 256 + lane * 4);
    ushort4 o;
    o.x = f2b(fmaxf(acc[0] * s + b2f(t2.x), 0.f));
    o.y = f2b(fmaxf(acc[1] * s + b2f(t2.y), 0.f));
    o.z = f2b(fmaxf(acc[2] * s + b2f(t2.z), 0.f));
    o.w = f2b(fmaxf(acc[3] * s + b2f(t2.w), 0.f));
    *(ushort4*)(h + (size_t)node * 256 + lane * 4) = o;
}

// ---------------- fused gather 2: out += mean(zb[nbr]) --------------------
__global__ __launch_bounds__(256) void fused_gather2(
    const ushort_t* __restrict__ zb, const int* __restrict__ rp,
    const int* __restrict__ col, float* __restrict__ out, int N)
{
    int gid  = blockIdx.x * blockDim.x + threadIdx.x;
    int node = gid >> 6;
    int lane = gid & 63;
    if (node >= N) return;
    int rs = rp[node], re = rp[node + 1];

    float acc[2] = {0.f, 0.f};
    for (int base = rs; base < re; base += 64) {
        int m = re - base; if (m > 64) m = 64;
        int c = (lane < m) ? col[base + lane] : 0;
        int j = 0;
        for (; j + 8 <= m; j += 8) {
            ushort2 tv[8];
            #pragma unroll
            for (int q = 0; q < 8; ++q) {
                int sq = __shfl(c, j + q);
                tv[q] = *(const ushort2*)(zb + (size_t)sq * 128 + lane * 2);
            }
            #pragma unroll
            for (int q = 0; q < 8; ++q) {
                acc[0] += b2f(tv[q].x); acc[1] += b2f(tv[q].y);
            }
        }
        for (; j < m; ++j) {
            int src = __shfl(c, j);
            ushort2 tq = *(const ushort2*)(zb + (size_t)src * 128 + lane * 2);
            acc[0] += b2f(tq.x); acc[1] += b2f(tq.y);
        }
    }

    float s = 1.0f / (float)max(re - rs, 1);
    float2 p = *(float2*)(out + (size_t)node * 128 + lane * 2);
    p.x += acc[0] * s; p.y += acc[1] * s;
    *(float2*)(out + (size_t)node * 128 + lane * 2) = p;
}

extern "C" void kernel_launch(void* const* d_in, const int* in_sizes, int n_in,
                              void* d_out, int out_size, void* d_ws, size_t ws_size,
                              hipStream_t stream)
{
    const float* x   = (const float*)d_in[0];
    const int*   ei  = (const int*)d_in[1];
    const float* W1l = (const float*)d_in[2];
    const float* b1  = (const float*)d_in[3];
    const float* W1r = (const float*)d_in[4];
    const float* W2l = (const float*)d_in[5];
    const float* b2  = (const float*)d_in[6];
    const float* W2r = (const float*)d_in[7];
    float* out = (float*)d_out;

    const int N = N_NODES, E = N_EDGES;

    // workspace layout (256 B aligned)
    const size_t off_deg  = 0;                               // int[50000]
    const size_t off_rp   = 204800;                          // int[50001]
    const size_t off_cur  = 409600;                          // int[50000]
    const size_t off_bsum = 614400;                          // int[256]
    const size_t off_col  = 615424;                          // int[800000]
    const size_t off_xb   = 3815424;                         // bf16 [N][256]; h overlays
    const size_t off_y    = off_xb + (size_t)N * 256 * 2;    // bf16 [N][512]; zb overlays
    const size_t off_bt1  = off_y  + (size_t)N * 512 * 2;
    const size_t off_bt2  = off_bt1 + 512 * 256 * 2;
    const size_t required = off_bt2 + 256 * 256 * 2;         // ~81 MB
    if (ws_size < required) return;

    char* ws = (char*)d_ws;
    int*      deg    = (int*)(ws + off_deg);
    int*      rp     = (int*)(ws + off_rp);
    int*      cursor = (int*)(ws + off_cur);
    int*      bsum   = (int*)(ws + off_bsum);
    int*      col    = (int*)(ws + off_col);
    ushort_t* xb     = (ushort_t*)(ws + off_xb);
    ushort_t* h      = (ushort_t*)(ws + off_xb);   // overlays xb (dead after GEMM1)
    ushort_t* y      = (ushort_t*)(ws + off_y);
    ushort_t* zb     = (ushort_t*)(ws + off_y);    // overlays y (dead after gather1)
    ushort_t* Bt1    = (ushort_t*)(ws + off_bt1);
    ushort_t* Bt2    = (ushort_t*)(ws + off_bt2);

    const int eb = (E + 255) / 256;
    const int nb = (N + SCAN_B - 1) / SCAN_B;
    const int mt = (N + 127) / 128;   // 391 row tiles

    // ---- CSR build ----
    hipMemsetAsync(deg, 0, (size_t)N * 4, stream);
    hipLaunchKernelGGL(edge_hist, dim3(eb), dim3(256), 0, stream, ei, deg, E);
    hipLaunchKernelGGL(scan1, dim3(nb), dim3(SCAN_B), 0, stream, deg, rp, bsum, N);
    hipLaunchKernelGGL(scan2, dim3(1), dim3(SCAN_B), 0, stream, bsum, nb);
    hipLaunchKernelGGL(scan3, dim3(nb), dim3(SCAN_B), 0, stream, rp, cursor, bsum, N, E);
    hipLaunchKernelGGL(edge_fill, dim3(eb), dim3(256), 0, stream, ei, cursor, col, E);

    // ---- casts ----
    hipLaunchKernelGGL(cast_f32_bf16, dim3(2048), dim3(256), 0, stream,
                       x, xb, N * 256 / 4);
    hipLaunchKernelGGL(build_bt, dim3(768), dim3(256), 0, stream,
                       W1l, W1r, W2l, W2r, Bt1, Bt2);

    // ---- layer 1: y = xb@[W1l|W1r] (+b1 on y2); h = relu(mean(y1)+y2) ----
    hipLaunchKernelGGL((gemm_mfma<0>), dim3(4, mt), dim3(256), 0, stream,
                       xb, Bt1, b1, y, (float*)nullptr, N);
    hipLaunchKernelGGL(fused_gather1, dim3((N + 3) / 4), dim3(256), 0, stream,
                       y, rp, col, h, N);

    // ---- layer 2: [zb|out] = h@[W2l|W2r] (+b2 on out); out += mean(zb) ----
    hipLaunchKernelGGL((gemm_mfma<1>), dim3(2, mt), dim3(256), 0, stream,
                       h, Bt2, b2, zb, out, N);
    hipLaunchKernelGGL(fused_gather2, dim3((N + 3) / 4), dim3(256), 0, stream,
                       zb, rp, col, out, N);
}

// Round 7
// 205.538 us; speedup vs baseline: 1.4493x; 1.3616x over previous
//
#include <hip/hip_runtime.h>

// GraphSAGE 2-layer forward.
// Round 7: CSR build rewritten as MSD bucket sort (LDS histograms + LDS
// counting sort) -- kills the 16x write-amplification / random-atomic cost
// of edge_hist+edge_fill (~100us -> ~30us). No global atomics, no memsets.
// GEMMs (128x128, BK=32, dbuf, vmcnt(4), 4 blk/CU) and gathers unchanged.

#define N_NODES 50000
#define N_EDGES 800000
#define RNB 196        // radix blocks == number of dst>>8 buckets
#define REPB 4096      // edges per radix block
#define BCAP 8192      // per-bucket capacity (avg 4082, sigma ~64)

typedef unsigned short ushort_t;
typedef __attribute__((ext_vector_type(8))) short short8v;   // 8 bf16
typedef __attribute__((ext_vector_type(4))) float f32x4;

__device__ __forceinline__ float b2f(ushort_t u) {
    union { unsigned int i; float f; } v; v.i = (unsigned int)u << 16; return v.f;
}
__device__ __forceinline__ ushort_t f2b(float f) {
    union { float f; unsigned int i; } v; v.f = f;
    unsigned int r = 0x7fffu + ((v.i >> 16) & 1u);   // RNE
    return (ushort_t)((v.i + r) >> 16);
}

__device__ __forceinline__ void gload_lds16(const void* gsrc, void* ldsdst) {
    auto* l3 = reinterpret_cast<__attribute__((address_space(3))) unsigned int*>(
        reinterpret_cast<uintptr_t>(ldsdst));
    __builtin_amdgcn_global_load_lds(
        reinterpret_cast<const unsigned int*>(gsrc), l3, 16, 0, 0);
}

// ---------------- CSR build via MSD bucket sort ----------------
// digit = dst >> 8  (dst < 50000 -> digit in [0,196))
__global__ __launch_bounds__(256) void mhist(
    const int* __restrict__ ei, int* __restrict__ ghist, int E)
{
    __shared__ int h[256];
    int t = threadIdx.x;
    h[t] = 0;
    __syncthreads();
    int base = blockIdx.x * REPB;
    int lim  = min(base + REPB, E);
    for (int i = base + t; i < lim; i += 256)
        atomicAdd(&h[ei[E + i] >> 8], 1);
    __syncthreads();
    if (t < RNB) ghist[t * RNB + blockIdx.x] = h[t];   // digit-major
}

#define SCAN_B 256
__global__ __launch_bounds__(256) void scan1(
    const int* __restrict__ in, int* __restrict__ excl,
    int* __restrict__ bsum, int N)
{
    __shared__ int s[SCAN_B];
    int t = threadIdx.x;
    int i = blockIdx.x * SCAN_B + t;
    int v = (i < N) ? in[i] : 0;
    s[t] = v;
    __syncthreads();
    for (int off = 1; off < SCAN_B; off <<= 1) {
        int add = (t >= off) ? s[t - off] : 0;
        __syncthreads();
        s[t] += add;
        __syncthreads();
    }
    if (i < N) excl[i] = s[t] - v;
    if (t == SCAN_B - 1) bsum[blockIdx.x] = s[t];
}

__global__ __launch_bounds__(256) void scan2(int* __restrict__ bsum, int nb)
{
    __shared__ int s[SCAN_B];
    int t = threadIdx.x;
    int v = (t < nb) ? bsum[t] : 0;
    s[t] = v;
    __syncthreads();
    for (int off = 1; off < SCAN_B; off <<= 1) {
        int add = (t >= off) ? s[t - off] : 0;
        __syncthreads();
        s[t] += add;
        __syncthreads();
    }
    if (t < nb) bsum[t] = s[t] - v;
}

__global__ __launch_bounds__(256) void scan3g(
    int* __restrict__ excl, const int* __restrict__ bsum, int N)
{
    int i = blockIdx.x * SCAN_B + threadIdx.x;
    if (i < N) excl[i] += bsum[blockIdx.x];
}

__global__ __launch_bounds__(256) void mscatter(
    const int* __restrict__ ei, const int* __restrict__ gscan,
    unsigned* __restrict__ packed, int E)
{
    __shared__ int cur[256];
    int t = threadIdx.x;
    if (t < RNB) cur[t] = gscan[t * RNB + blockIdx.x];
    __syncthreads();
    int base = blockIdx.x * REPB;
    int lim  = min(base + REPB, E);
    for (int i = base + t; i < lim; i += 256) {
        int d = ei[E + i], s = ei[i];
        int pos = atomicAdd(&cur[d >> 8], 1);
        packed[pos] = ((unsigned)d << 16) | (unsigned)s;
    }
}

// one block per bucket: in-LDS counting sort by dst&255; per-digit scan
// directly yields rp[dst]; col written coalesced from LDS.
__global__ __launch_bounds__(256) void bucket_sort(
    const unsigned* __restrict__ packed, const int* __restrict__ gscan,
    int* __restrict__ col, int* __restrict__ rp, int E)
{
    __shared__ unsigned k1[BCAP];
    __shared__ unsigned k2[BCAP];
    __shared__ int h[256], ss[256], ex[256], cur[256];

    int b = blockIdx.x, t = threadIdx.x;
    int start = gscan[b * RNB];
    int end   = (b + 1 < RNB) ? gscan[(b + 1) * RNB] : E;
    int sz    = min(end - start, BCAP);

    for (int i = t; i < sz; i += 256) k1[i] = packed[start + i];
    h[t] = 0;
    __syncthreads();
    for (int i = t; i < sz; i += 256)
        atomicAdd(&h[(k1[i] >> 16) & 255], 1);
    __syncthreads();
    ss[t] = h[t];
    __syncthreads();
    for (int off = 1; off < 256; off <<= 1) {
        int add = (t >= off) ? ss[t - off] : 0;
        __syncthreads();
        ss[t] += add;
        __syncthreads();
    }
    ex[t] = ss[t] - h[t];
    cur[t] = ex[t];
    __syncthreads();
    for (int i = t; i < sz; i += 256) {
        unsigned key = k1[i];
        int pos = atomicAdd(&cur[(key >> 16) & 255], 1);
        k2[pos] = key;
    }
    __syncthreads();
    for (int i = t; i < sz; i += 256)
        col[start + i] = (int)(k2[i] & 0xFFFFu);
    int dst = (b << 8) + t;
    if (dst <= N_NODES) rp[dst] = start + ex[t];
}

// ---------------- casts ----------------
__global__ __launch_bounds__(256) void cast_f32_bf16(
    const float* __restrict__ in, ushort_t* __restrict__ out, int n4)
{
    int i = blockIdx.x * blockDim.x + threadIdx.x;
    int stride = gridDim.x * blockDim.x;
    for (; i < n4; i += stride) {
        float4 v = ((const float4*)in)[i];
        ushort4 o;
        o.x = f2b(v.x); o.y = f2b(v.y); o.z = f2b(v.z); o.w = f2b(v.w);
        ((ushort4*)out)[i] = o;
    }
}

// Bt1[512][256] = [W1l|W1r]^T ; Bt2[256][256] = [W2l|W2r]^T  (bf16, [n][k])
__global__ __launch_bounds__(256) void build_bt(
    const float* __restrict__ W1l, const float* __restrict__ W1r,
    const float* __restrict__ W2l, const float* __restrict__ W2r,
    ushort_t* __restrict__ Bt1, ushort_t* __restrict__ Bt2)
{
    int i = blockIdx.x * 256 + threadIdx.x;
    if (i < 512 * 256) {
        int n = i >> 8, k = i & 255;
        float v = (n < 256) ? W1l[k * 256 + n] : W1r[k * 256 + (n - 256)];
        Bt1[i] = f2b(v);
    }
    int j = i - 512 * 256;
    if (j >= 0 && j < 256 * 256) {
        int n = j >> 8, k = j & 255;
        float v = (n < 128) ? W2l[k * 128 + n] : W2r[k * 128 + (n - 128)];
        Bt2[j] = f2b(v);
    }
}

// ---------------- bf16 MFMA GEMM: 128x128 tile, BK=32, dbuf, 4 waves ------
template<int MODE>
__global__ __launch_bounds__(256, 4) void gemm_mfma(
    const ushort_t* __restrict__ A, const ushort_t* __restrict__ Bt,
    const float* __restrict__ bias,
    ushort_t* __restrict__ outb, float* __restrict__ outf, int M)
{
    __shared__ ushort_t As[2][128][32];   // 2 x 8 KB, row = 64 B
    __shared__ ushort_t Bs[2][128][32];

    const int t    = threadIdx.x;
    const int lane = t & 63;
    const int w    = t >> 6;
    const int wr   = w >> 1, wc = w & 1;
    const int col0 = blockIdx.x * 128;    // col fastest -> A-slab L2 reuse
    const int row0 = blockIdx.y * 128;

    f32x4 acc[4][4] = {};

    auto stage = [&](int kt, int buf) {
        const int kA = kt * 32;
        #pragma unroll
        for (int i = 0; i < 2; ++i) {
            int idx  = i * 256 + t;
            int row  = idx >> 2;
            int kb   = ((idx & 3) * 16) ^ ((row & 3) << 4);
            int grow = row0 + row; if (grow >= M) grow = M - 1;
            gload_lds16(A + (size_t)grow * 256 + kA + (kb >> 1),
                        (char*)&As[buf][0][0] + i * 4096 + w * 1024);
        }
        #pragma unroll
        for (int i = 0; i < 2; ++i) {
            int idx = i * 256 + t;
            int row = idx >> 2;
            int kb  = ((idx & 3) * 16) ^ ((row & 3) << 4);
            gload_lds16(Bt + (size_t)(col0 + row) * 256 + kA + (kb >> 1),
                        (char*)&Bs[buf][0][0] + i * 4096 + w * 1024);
        }
    };

    stage(0, 0);
    #pragma unroll
    for (int kt = 0; kt < 8; ++kt) {
        const int buf = kt & 1;
        if (kt < 7) {
            stage(kt + 1, buf ^ 1);
            asm volatile("s_waitcnt vmcnt(4)");
        } else {
            asm volatile("s_waitcnt vmcnt(0)");
        }
        __builtin_amdgcn_sched_barrier(0);
        __builtin_amdgcn_s_barrier();
        __builtin_amdgcn_sched_barrier(0);

        short8v af[4], bg[4];
        #pragma unroll
        for (int mi = 0; mi < 4; ++mi) {
            int r = (wr << 6) + (mi << 4) + (lane & 15);
            int b = (((lane >> 4) << 4)) ^ ((r & 3) << 4);
            af[mi] = *(const short8v*)((const char*)&As[buf][0][0] + r * 64 + b);
        }
        #pragma unroll
        for (int nj = 0; nj < 4; ++nj) {
            int r = (wc << 6) + (nj << 4) + (lane & 15);
            int b = (((lane >> 4) << 4)) ^ ((r & 3) << 4);
            bg[nj] = *(const short8v*)((const char*)&Bs[buf][0][0] + r * 64 + b);
        }

        __builtin_amdgcn_s_setprio(1);
        #pragma unroll
        for (int mi = 0; mi < 4; ++mi)
            #pragma unroll
            for (int nj = 0; nj < 4; ++nj)
                acc[mi][nj] = __builtin_amdgcn_mfma_f32_16x16x32_bf16(
                    af[mi], bg[nj], acc[mi][nj], 0, 0, 0);
        __builtin_amdgcn_s_setprio(0);

        __builtin_amdgcn_sched_barrier(0);
        __builtin_amdgcn_s_barrier();
        __builtin_amdgcn_sched_barrier(0);
    }

    #pragma unroll
    for (int mi = 0; mi < 4; ++mi) {
        #pragma unroll
        for (int nj = 0; nj < 4; ++nj) {
            int c = col0 + (wc << 6) + (nj << 4) + (lane & 15);
            #pragma unroll
            for (int r = 0; r < 4; ++r) {
                int row = row0 + (wr << 6) + (mi << 4) + ((lane >> 4) << 2) + r;
                if (row >= M) continue;
                float v = acc[mi][nj][r];
                if (MODE == 0) {
                    if (c >= 256) v += bias[c - 256];
                    outb[(size_t)row * 512 + c] = f2b(v);
                } else {
                    if (c < 128) {
                        outb[(size_t)row * 128 + c] = f2b(v);
                    } else {
                        outf[(size_t)row * 128 + (c - 128)] = v + bias[c - 128];
                    }
                }
            }
        }
    }
}

// ---------------- fused gather 1: h = relu(mean(y1[nbr]) + y2) ------------
__global__ __launch_bounds__(256) void fused_gather1(
    const ushort_t* __restrict__ y, const int* __restrict__ rp,
    const int* __restrict__ col, ushort_t* __restrict__ h, int N)
{
    int gid  = blockIdx.x * blockDim.x + threadIdx.x;
    int node = gid >> 6;
    int lane = gid & 63;
    if (node >= N) return;
    int rs = rp[node], re = rp[node + 1];

    float acc[4] = {0.f, 0.f, 0.f, 0.f};
    for (int base = rs; base < re; base += 64) {
        int m = re - base; if (m > 64) m = 64;
        int c = (lane < m) ? col[base + lane] : 0;
        int j = 0;
        for (; j + 8 <= m; j += 8) {
            ushort4 tv[8];
            #pragma unroll
            for (int q = 0; q < 8; ++q) {
                int sq = __shfl(c, j + q);
                tv[q] = *(const ushort4*)(y + (size_t)sq * 512 + lane * 4);
            }
            #pragma unroll
            for (int q = 0; q < 8; ++q) {
                acc[0] += b2f(tv[q].x); acc[1] += b2f(tv[q].y);
                acc[2] += b2f(tv[q].z); acc[3] += b2f(tv[q].w);
            }
        }
        for (; j < m; ++j) {
            int src = __shfl(c, j);
            ushort4 tq = *(const ushort4*)(y + (size_t)src * 512 + lane * 4);
            acc[0] += b2f(tq.x); acc[1] += b2f(tq.y);
            acc[2] += b2f(tq.z); acc[3] += b2f(tq.w);
        }
    }

    float s = 1.0f / (float)max(re - rs, 1);
    ushort4 t2 = *(const ushort4*)(y + (size_t)node * 512 + 256 + lane * 4);
    ushort4 o;
    o.x = f2b(fmaxf(acc[0] * s + b2f(t2.x), 0.f));
    o.y = f2b(fmaxf(acc[1] * s + b2f(t2.y), 0.f));
    o.z = f2b(fmaxf(acc[2] * s + b2f(t2.z), 0.f));
    o.w = f2b(fmaxf(acc[3] * s + b2f(t2.w), 0.f));
    *(ushort4*)(h + (size_t)node * 256 + lane * 4) = o;
}

// ---------------- fused gather 2: out += mean(zb[nbr]) --------------------
__global__ __launch_bounds__(256) void fused_gather2(
    const ushort_t* __restrict__ zb, const int* __restrict__ rp,
    const int* __restrict__ col, float* __restrict__ out, int N)
{
    int gid  = blockIdx.x * blockDim.x + threadIdx.x;
    int node = gid >> 6;
    int lane = gid & 63;
    if (node >= N) return;
    int rs = rp[node], re = rp[node + 1];

    float acc[2] = {0.f, 0.f};
    for (int base = rs; base < re; base += 64) {
        int m = re - base; if (m > 64) m = 64;
        int c = (lane < m) ? col[base + lane] : 0;
        int j = 0;
        for (; j + 8 <= m; j += 8) {
            ushort2 tv[8];
            #pragma unroll
            for (int q = 0; q < 8; ++q) {
                int sq = __shfl(c, j + q);
                tv[q] = *(const ushort2*)(zb + (size_t)sq * 128 + lane * 2);
            }
            #pragma unroll
            for (int q = 0; q < 8; ++q) {
                acc[0] += b2f(tv[q].x); acc[1] += b2f(tv[q].y);
            }
        }
        for (; j < m; ++j) {
            int src = __shfl(c, j);
            ushort2 tq = *(const ushort2*)(zb + (size_t)src * 128 + lane * 2);
            acc[0] += b2f(tq.x); acc[1] += b2f(tq.y);
        }
    }

    float s = 1.0f / (float)max(re - rs, 1);
    float2 p = *(float2*)(out + (size_t)node * 128 + lane * 2);
    p.x += acc[0] * s; p.y += acc[1] * s;
    *(float2*)(out + (size_t)node * 128 + lane * 2) = p;
}

extern "C" void kernel_launch(void* const* d_in, const int* in_sizes, int n_in,
                              void* d_out, int out_size, void* d_ws, size_t ws_size,
                              hipStream_t stream)
{
    const float* x   = (const float*)d_in[0];
    const int*   ei  = (const int*)d_in[1];
    const float* W1l = (const float*)d_in[2];
    const float* b1  = (const float*)d_in[3];
    const float* W1r = (const float*)d_in[4];
    const float* W2l = (const float*)d_in[5];
    const float* b2  = (const float*)d_in[6];
    const float* W2r = (const float*)d_in[7];
    float* out = (float*)d_out;

    const int N = N_NODES, E = N_EDGES;
    const int HTOT = RNB * RNB;                  // 38416 hist counters

    // workspace layout (256 B aligned)
    const size_t off_rp     = 0;                 // int[50001]
    const size_t off_col    = 204800;            // int[800000]
    const size_t off_packed = off_col + 3200000; // u32[800000]
    const size_t off_ghist  = off_packed + 3200000;
    const size_t off_gscan  = off_ghist + 160000;
    const size_t off_bsumR  = off_gscan + 160000;
    const size_t off_xb     = off_bsumR + 2048;              // bf16 [N][256]; h overlays
    const size_t off_y      = off_xb + (size_t)N * 256 * 2;  // bf16 [N][512]; zb overlays
    const size_t off_bt1    = off_y  + (size_t)N * 512 * 2;
    const size_t off_bt2    = off_bt1 + 512 * 256 * 2;
    const size_t required   = off_bt2 + 256 * 256 * 2;       // ~84 MB
    if (ws_size < required) return;

    char* ws = (char*)d_ws;
    int*      rp     = (int*)(ws + off_rp);
    int*      col    = (int*)(ws + off_col);
    unsigned* packed = (unsigned*)(ws + off_packed);
    int*      ghist  = (int*)(ws + off_ghist);
    int*      gscan  = (int*)(ws + off_gscan);
    int*      bsumR  = (int*)(ws + off_bsumR);
    ushort_t* xb     = (ushort_t*)(ws + off_xb);
    ushort_t* h      = (ushort_t*)(ws + off_xb);   // overlays xb (dead after GEMM1)
    ushort_t* y      = (ushort_t*)(ws + off_y);
    ushort_t* zb     = (ushort_t*)(ws + off_y);    // overlays y (dead after gather1)
    ushort_t* Bt1    = (ushort_t*)(ws + off_bt1);
    ushort_t* Bt2    = (ushort_t*)(ws + off_bt2);

    const int snb = (HTOT + SCAN_B - 1) / SCAN_B;   // 151
    const int mt  = (N + 127) / 128;                // 391 row tiles

    // ---- CSR build: MSD bucket sort ----
    hipLaunchKernelGGL(mhist, dim3(RNB), dim3(256), 0, stream, ei, ghist, E);
    hipLaunchKernelGGL(scan1, dim3(snb), dim3(SCAN_B), 0, stream, ghist, gscan, bsumR, HTOT);
    hipLaunchKernelGGL(scan2, dim3(1), dim3(SCAN_B), 0, stream, bsumR, snb);
    hipLaunchKernelGGL(scan3g, dim3(snb), dim3(SCAN_B), 0, stream, gscan, bsumR, HTOT);
    hipLaunchKernelGGL(mscatter, dim3(RNB), dim3(256), 0, stream, ei, gscan, packed, E);
    hipLaunchKernelGGL(bucket_sort, dim3(RNB), dim3(256), 0, stream, packed, gscan, col, rp, E);

    // ---- casts ----
    hipLaunchKernelGGL(cast_f32_bf16, dim3(2048), dim3(256), 0, stream,
                       x, xb, N * 256 / 4);
    hipLaunchKernelGGL(build_bt, dim3(768), dim3(256), 0, stream,
                       W1l, W1r, W2l, W2r, Bt1, Bt2);

    // ---- layer 1: y = xb@[W1l|W1r] (+b1 on y2); h = relu(mean(y1)+y2) ----
    hipLaunchKernelGGL((gemm_mfma<0>), dim3(4, mt), dim3(256), 0, stream,
                       xb, Bt1, b1, y, (float*)nullptr, N);
    hipLaunchKernelGGL(fused_gather1, dim3((N + 3) / 4), dim3(256), 0, stream,
                       y, rp, col, h, N);

    // ---- layer 2: [zb|out] = h@[W2l|W2r] (+b2 on out); out += mean(zb) ----
    hipLaunchKernelGGL((gemm_mfma<1>), dim3(2, mt), dim3(256), 0, stream,
                       h, Bt2, b2, zb, out, N);
    hipLaunchKernelGGL(fused_gather2, dim3((N + 3) / 4), dim3(256), 0, stream,
                       zb, rp, col, out, N);
}

// Round 8
// 181.777 us; speedup vs baseline: 1.6387x; 1.1307x over previous
//
#include <hip/hip_runtime.h>

// GraphSAGE 2-layer forward.
// Round 8: y1 (gather1's feed) stored as fp8 e4m3 -- halves the dominant
// gather's L3 traffic (410->205 MB logical) and halves decode VALU via
// v_cvt_pk_f32_fp8. fp8 error attenuates through W2 (safe even for deg-1
// nodes); zb stays bf16 (it feeds the output directly). Everything else
// unchanged from round 7.

#define N_NODES 50000
#define N_EDGES 800000
#define RNB 196        // radix blocks == number of dst>>8 buckets
#define REPB 4096      // edges per radix block
#define BCAP 8192      // per-bucket capacity (avg 4082, sigma ~64)

typedef unsigned short ushort_t;
typedef __attribute__((ext_vector_type(8))) short short8v;   // 8 bf16
typedef __attribute__((ext_vector_type(4))) float f32x4;
typedef __attribute__((ext_vector_type(2))) float f32x2;

__device__ __forceinline__ float b2f(ushort_t u) {
    union { unsigned int i; float f; } v; v.i = (unsigned int)u << 16; return v.f;
}
__device__ __forceinline__ ushort_t f2b(float f) {
    union { float f; unsigned int i; } v; v.f = f;
    unsigned int r = 0x7fffu + ((v.i >> 16) & 1u);   // RNE
    return (ushort_t)((v.i + r) >> 16);
}

__device__ __forceinline__ void gload_lds16(const void* gsrc, void* ldsdst) {
    auto* l3 = reinterpret_cast<__attribute__((address_space(3))) unsigned int*>(
        reinterpret_cast<uintptr_t>(ldsdst));
    __builtin_amdgcn_global_load_lds(
        reinterpret_cast<const unsigned int*>(gsrc), l3, 16, 0, 0);
}

// ---------------- CSR build via MSD bucket sort ----------------
__global__ __launch_bounds__(256) void mhist(
    const int* __restrict__ ei, int* __restrict__ ghist, int E)
{
    __shared__ int h[256];
    int t = threadIdx.x;
    h[t] = 0;
    __syncthreads();
    int base = blockIdx.x * REPB;
    int lim  = min(base + REPB, E);
    for (int i = base + t; i < lim; i += 256)
        atomicAdd(&h[ei[E + i] >> 8], 1);
    __syncthreads();
    if (t < RNB) ghist[t * RNB + blockIdx.x] = h[t];   // digit-major
}

#define SCAN_B 256
__global__ __launch_bounds__(256) void scan1(
    const int* __restrict__ in, int* __restrict__ excl,
    int* __restrict__ bsum, int N)
{
    __shared__ int s[SCAN_B];
    int t = threadIdx.x;
    int i = blockIdx.x * SCAN_B + t;
    int v = (i < N) ? in[i] : 0;
    s[t] = v;
    __syncthreads();
    for (int off = 1; off < SCAN_B; off <<= 1) {
        int add = (t >= off) ? s[t - off] : 0;
        __syncthreads();
        s[t] += add;
        __syncthreads();
    }
    if (i < N) excl[i] = s[t] - v;
    if (t == SCAN_B - 1) bsum[blockIdx.x] = s[t];
}

__global__ __launch_bounds__(256) void scan2(int* __restrict__ bsum, int nb)
{
    __shared__ int s[SCAN_B];
    int t = threadIdx.x;
    int v = (t < nb) ? bsum[t] : 0;
    s[t] = v;
    __syncthreads();
    for (int off = 1; off < 256; off <<= 1) {
        int add = (t >= off) ? s[t - off] : 0;
        __syncthreads();
        s[t] += add;
        __syncthreads();
    }
    if (t < nb) bsum[t] = s[t] - v;
}

__global__ __launch_bounds__(256) void scan3g(
    int* __restrict__ excl, const int* __restrict__ bsum, int N)
{
    int i = blockIdx.x * SCAN_B + threadIdx.x;
    if (i < N) excl[i] += bsum[blockIdx.x];
}

__global__ __launch_bounds__(256) void mscatter(
    const int* __restrict__ ei, const int* __restrict__ gscan,
    unsigned* __restrict__ packed, int E)
{
    __shared__ int cur[256];
    int t = threadIdx.x;
    if (t < RNB) cur[t] = gscan[t * RNB + blockIdx.x];
    __syncthreads();
    int base = blockIdx.x * REPB;
    int lim  = min(base + REPB, E);
    for (int i = base + t; i < lim; i += 256) {
        int d = ei[E + i], s = ei[i];
        int pos = atomicAdd(&cur[d >> 8], 1);
        packed[pos] = ((unsigned)d << 16) | (unsigned)s;
    }
}

__global__ __launch_bounds__(256) void bucket_sort(
    const unsigned* __restrict__ packed, const int* __restrict__ gscan,
    int* __restrict__ col, int* __restrict__ rp, int E)
{
    __shared__ unsigned k1[BCAP];
    __shared__ unsigned k2[BCAP];
    __shared__ int h[256], ss[256], ex[256], cur[256];

    int b = blockIdx.x, t = threadIdx.x;
    int start = gscan[b * RNB];
    int end   = (b + 1 < RNB) ? gscan[(b + 1) * RNB] : E;
    int sz    = min(end - start, BCAP);

    for (int i = t; i < sz; i += 256) k1[i] = packed[start + i];
    h[t] = 0;
    __syncthreads();
    for (int i = t; i < sz; i += 256)
        atomicAdd(&h[(k1[i] >> 16) & 255], 1);
    __syncthreads();
    ss[t] = h[t];
    __syncthreads();
    for (int off = 1; off < 256; off <<= 1) {
        int add = (t >= off) ? ss[t - off] : 0;
        __syncthreads();
        ss[t] += add;
        __syncthreads();
    }
    ex[t] = ss[t] - h[t];
    cur[t] = ex[t];
    __syncthreads();
    for (int i = t; i < sz; i += 256) {
        unsigned key = k1[i];
        int pos = atomicAdd(&cur[(key >> 16) & 255], 1);
        k2[pos] = key;
    }
    __syncthreads();
    for (int i = t; i < sz; i += 256)
        col[start + i] = (int)(k2[i] & 0xFFFFu);
    int dst = (b << 8) + t;
    if (dst <= N_NODES) rp[dst] = start + ex[t];
}

// ---------------- casts ----------------
__global__ __launch_bounds__(256) void cast_f32_bf16(
    const float* __restrict__ in, ushort_t* __restrict__ out, int n4)
{
    int i = blockIdx.x * blockDim.x + threadIdx.x;
    int stride = gridDim.x * blockDim.x;
    for (; i < n4; i += stride) {
        float4 v = ((const float4*)in)[i];
        ushort4 o;
        o.x = f2b(v.x); o.y = f2b(v.y); o.z = f2b(v.z); o.w = f2b(v.w);
        ((ushort4*)out)[i] = o;
    }
}

// Bt1[512][256] = [W1l|W1r]^T ; Bt2[256][256] = [W2l|W2r]^T  (bf16, [n][k])
__global__ __launch_bounds__(256) void build_bt(
    const float* __restrict__ W1l, const float* __restrict__ W1r,
    const float* __restrict__ W2l, const float* __restrict__ W2r,
    ushort_t* __restrict__ Bt1, ushort_t* __restrict__ Bt2)
{
    int i = blockIdx.x * 256 + threadIdx.x;
    if (i < 512 * 256) {
        int n = i >> 8, k = i & 255;
        float v = (n < 256) ? W1l[k * 256 + n] : W1r[k * 256 + (n - 256)];
        Bt1[i] = f2b(v);
    }
    int j = i - 512 * 256;
    if (j >= 0 && j < 256 * 256) {
        int n = j >> 8, k = j & 255;
        float v = (n < 128) ? W2l[k * 128 + n] : W2r[k * 128 + (n - 128)];
        Bt2[j] = f2b(v);
    }
}

// ---------------- bf16 MFMA GEMM: 128x128 tile, BK=32, dbuf, 4 waves ------
// MODE 0: c<256 -> out8 fp8 e4m3 (y1, ld 256); c>=256 -> outb bf16 (y2, ld
//         256, +bias = b1 folded).
// MODE 1: c<128 -> outb bf16 (zb, ld 128); c>=128 -> outf f32 (out, ld 128,
//         +bias = b2).
template<int MODE>
__global__ __launch_bounds__(256, 4) void gemm_mfma(
    const ushort_t* __restrict__ A, const ushort_t* __restrict__ Bt,
    const float* __restrict__ bias, unsigned char* __restrict__ out8,
    ushort_t* __restrict__ outb, float* __restrict__ outf, int M)
{
    __shared__ ushort_t As[2][128][32];   // 2 x 8 KB, row = 64 B
    __shared__ ushort_t Bs[2][128][32];

    const int t    = threadIdx.x;
    const int lane = t & 63;
    const int w    = t >> 6;
    const int wr   = w >> 1, wc = w & 1;
    const int col0 = blockIdx.x * 128;    // col fastest -> A-slab L2 reuse
    const int row0 = blockIdx.y * 128;

    f32x4 acc[4][4] = {};

    auto stage = [&](int kt, int buf) {
        const int kA = kt * 32;
        #pragma unroll
        for (int i = 0; i < 2; ++i) {
            int idx  = i * 256 + t;
            int row  = idx >> 2;
            int kb   = ((idx & 3) * 16) ^ ((row & 3) << 4);
            int grow = row0 + row; if (grow >= M) grow = M - 1;
            gload_lds16(A + (size_t)grow * 256 + kA + (kb >> 1),
                        (char*)&As[buf][0][0] + i * 4096 + w * 1024);
        }
        #pragma unroll
        for (int i = 0; i < 2; ++i) {
            int idx = i * 256 + t;
            int row = idx >> 2;
            int kb  = ((idx & 3) * 16) ^ ((row & 3) << 4);
            gload_lds16(Bt + (size_t)(col0 + row) * 256 + kA + (kb >> 1),
                        (char*)&Bs[buf][0][0] + i * 4096 + w * 1024);
        }
    };

    stage(0, 0);
    #pragma unroll
    for (int kt = 0; kt < 8; ++kt) {
        const int buf = kt & 1;
        if (kt < 7) {
            stage(kt + 1, buf ^ 1);
            asm volatile("s_waitcnt vmcnt(4)");
        } else {
            asm volatile("s_waitcnt vmcnt(0)");
        }
        __builtin_amdgcn_sched_barrier(0);
        __builtin_amdgcn_s_barrier();
        __builtin_amdgcn_sched_barrier(0);

        short8v af[4], bg[4];
        #pragma unroll
        for (int mi = 0; mi < 4; ++mi) {
            int r = (wr << 6) + (mi << 4) + (lane & 15);
            int b = (((lane >> 4) << 4)) ^ ((r & 3) << 4);
            af[mi] = *(const short8v*)((const char*)&As[buf][0][0] + r * 64 + b);
        }
        #pragma unroll
        for (int nj = 0; nj < 4; ++nj) {
            int r = (wc << 6) + (nj << 4) + (lane & 15);
            int b = (((lane >> 4) << 4)) ^ ((r & 3) << 4);
            bg[nj] = *(const short8v*)((const char*)&Bs[buf][0][0] + r * 64 + b);
        }

        __builtin_amdgcn_s_setprio(1);
        #pragma unroll
        for (int mi = 0; mi < 4; ++mi)
            #pragma unroll
            for (int nj = 0; nj < 4; ++nj)
                acc[mi][nj] = __builtin_amdgcn_mfma_f32_16x16x32_bf16(
                    af[mi], bg[nj], acc[mi][nj], 0, 0, 0);
        __builtin_amdgcn_s_setprio(0);

        __builtin_amdgcn_sched_barrier(0);
        __builtin_amdgcn_s_barrier();
        __builtin_amdgcn_sched_barrier(0);
    }

    #pragma unroll
    for (int mi = 0; mi < 4; ++mi) {
        #pragma unroll
        for (int nj = 0; nj < 4; ++nj) {
            int c = col0 + (wc << 6) + (nj << 4) + (lane & 15);
            #pragma unroll
            for (int r = 0; r < 4; ++r) {
                int row = row0 + (wr << 6) + (mi << 4) + ((lane >> 4) << 2) + r;
                if (row >= M) continue;
                float v = acc[mi][nj][r];
                if (MODE == 0) {
                    if (c < 256) {
                        unsigned p = __builtin_amdgcn_cvt_pk_fp8_f32(v, v, 0, false);
                        out8[(size_t)row * 256 + c] = (unsigned char)(p & 0xFFu);
                    } else {
                        outb[(size_t)row * 256 + (c - 256)] = f2b(v + bias[c - 256]);
                    }
                } else {
                    if (c < 128) {
                        outb[(size_t)row * 128 + c] = f2b(v);
                    } else {
                        outf[(size_t)row * 128 + (c - 128)] = v + bias[c - 128];
                    }
                }
            }
        }
    }
}

// ---------------- fused gather 1: h = relu(mean_fp8(y1[nbr]) + y2) --------
// y8: [N][256] fp8 e4m3 ; y2b: [N][256] bf16. lane covers cols lane*4..+3.
__global__ __launch_bounds__(256) void fused_gather1(
    const unsigned char* __restrict__ y8, const ushort_t* __restrict__ y2b,
    const int* __restrict__ rp, const int* __restrict__ col,
    ushort_t* __restrict__ h, int N)
{
    int gid  = blockIdx.x * blockDim.x + threadIdx.x;
    int node = gid >> 6;
    int lane = gid & 63;
    if (node >= N) return;
    int rs = rp[node], re = rp[node + 1];

    float acc[4] = {0.f, 0.f, 0.f, 0.f};
    for (int base = rs; base < re; base += 64) {
        int m = re - base; if (m > 64) m = 64;
        int c = (lane < m) ? col[base + lane] : 0;
        int j = 0;
        for (; j + 8 <= m; j += 8) {     // 8 row-loads in flight
            unsigned tv[8];
            #pragma unroll
            for (int q = 0; q < 8; ++q) {
                int sq = __shfl(c, j + q);
                tv[q] = *(const unsigned*)(y8 + (size_t)sq * 256 + lane * 4);
            }
            #pragma unroll
            for (int q = 0; q < 8; ++q) {
                f32x2 lo = __builtin_amdgcn_cvt_pk_f32_fp8(tv[q], false);
                f32x2 hi = __builtin_amdgcn_cvt_pk_f32_fp8(tv[q], true);
                acc[0] += lo[0]; acc[1] += lo[1];
                acc[2] += hi[0]; acc[3] += hi[1];
            }
        }
        for (; j < m; ++j) {
            int sq = __shfl(c, j);
            unsigned tq = *(const unsigned*)(y8 + (size_t)sq * 256 + lane * 4);
            f32x2 lo = __builtin_amdgcn_cvt_pk_f32_fp8(tq, false);
            f32x2 hi = __builtin_amdgcn_cvt_pk_f32_fp8(tq, true);
            acc[0] += lo[0]; acc[1] += lo[1];
            acc[2] += hi[0]; acc[3] += hi[1];
        }
    }

    float s = 1.0f / (float)max(re - rs, 1);
    ushort4 t2 = *(const ushort4*)(y2b + (size_t)node * 256 + lane * 4);
    ushort4 o;
    o.x = f2b(fmaxf(acc[0] * s + b2f(t2.x), 0.f));
    o.y = f2b(fmaxf(acc[1] * s + b2f(t2.y), 0.f));
    o.z = f2b(fmaxf(acc[2] * s + b2f(t2.z), 0.f));
    o.w = f2b(fmaxf(acc[3] * s + b2f(t2.w), 0.f));
    *(ushort4*)(h + (size_t)node * 256 + lane * 4) = o;
}

// ---------------- fused gather 2: out += mean(zb[nbr]) --------------------
__global__ __launch_bounds__(256) void fused_gather2(
    const ushort_t* __restrict__ zb, const int* __restrict__ rp,
    const int* __restrict__ col, float* __restrict__ out, int N)
{
    int gid  = blockIdx.x * blockDim.x + threadIdx.x;
    int node = gid >> 6;
    int lane = gid & 63;
    if (node >= N) return;
    int rs = rp[node], re = rp[node + 1];

    float acc[2] = {0.f, 0.f};
    for (int base = rs; base < re; base += 64) {
        int m = re - base; if (m > 64) m = 64;
        int c = (lane < m) ? col[base + lane] : 0;
        int j = 0;
        for (; j + 8 <= m; j += 8) {
            ushort2 tv[8];
            #pragma unroll
            for (int q = 0; q < 8; ++q) {
                int sq = __shfl(c, j + q);
                tv[q] = *(const ushort2*)(zb + (size_t)sq * 128 + lane * 2);
            }
            #pragma unroll
            for (int q = 0; q < 8; ++q) {
                acc[0] += b2f(tv[q].x); acc[1] += b2f(tv[q].y);
            }
        }
        for (; j < m; ++j) {
            int src = __shfl(c, j);
            ushort2 tq = *(const ushort2*)(zb + (size_t)src * 128 + lane * 2);
            acc[0] += b2f(tq.x); acc[1] += b2f(tq.y);
        }
    }

    float s = 1.0f / (float)max(re - rs, 1);
    float2 p = *(float2*)(out + (size_t)node * 128 + lane * 2);
    p.x += acc[0] * s; p.y += acc[1] * s;
    *(float2*)(out + (size_t)node * 128 + lane * 2) = p;
}

extern "C" void kernel_launch(void* const* d_in, const int* in_sizes, int n_in,
                              void* d_out, int out_size, void* d_ws, size_t ws_size,
                              hipStream_t stream)
{
    const float* x   = (const float*)d_in[0];
    const int*   ei  = (const int*)d_in[1];
    const float* W1l = (const float*)d_in[2];
    const float* b1  = (const float*)d_in[3];
    const float* W1r = (const float*)d_in[4];
    const float* W2l = (const float*)d_in[5];
    const float* b2  = (const float*)d_in[6];
    const float* W2r = (const float*)d_in[7];
    float* out = (float*)d_out;

    const int N = N_NODES, E = N_EDGES;
    const int HTOT = RNB * RNB;                  // 38416 hist counters

    // workspace layout (256 B aligned)
    const size_t off_rp     = 0;                 // int[50001]
    const size_t off_col    = 204800;            // int[800000]
    const size_t off_packed = off_col + 3200000;
    const size_t off_ghist  = off_packed + 3200000;
    const size_t off_gscan  = off_ghist + 160000;
    const size_t off_bsumR  = off_gscan + 160000;
    const size_t off_xb     = off_bsumR + 2048;                // bf16 [N][256]; h overlays
    const size_t off_y8     = off_xb  + (size_t)N * 256 * 2;   // fp8  [N][256]; zb overlays
    const size_t off_y2b    = off_y8  + (size_t)N * 256;       // bf16 [N][256]
    const size_t off_bt1    = off_y2b + (size_t)N * 256 * 2;
    const size_t off_bt2    = off_bt1 + 512 * 256 * 2;
    const size_t required   = off_bt2 + 256 * 256 * 2;         // ~71.3 MB
    if (ws_size < required) return;

    char* ws = (char*)d_ws;
    int*           rp     = (int*)(ws + off_rp);
    int*           col    = (int*)(ws + off_col);
    unsigned*      packed = (unsigned*)(ws + off_packed);
    int*           ghist  = (int*)(ws + off_ghist);
    int*           gscan  = (int*)(ws + off_gscan);
    int*           bsumR  = (int*)(ws + off_bsumR);
    ushort_t*      xb     = (ushort_t*)(ws + off_xb);
    ushort_t*      h      = (ushort_t*)(ws + off_xb);  // overlays xb (dead after GEMM1)
    unsigned char* y8     = (unsigned char*)(ws + off_y8);
    ushort_t*      zb     = (ushort_t*)(ws + off_y8);  // overlays y8 (dead after gather1)
    ushort_t*      y2b    = (ushort_t*)(ws + off_y2b);
    ushort_t*      Bt1    = (ushort_t*)(ws + off_bt1);
    ushort_t*      Bt2    = (ushort_t*)(ws + off_bt2);

    const int snb = (HTOT + SCAN_B - 1) / SCAN_B;   // 151
    const int mt  = (N + 127) / 128;                // 391 row tiles

    // ---- CSR build: MSD bucket sort ----
    hipLaunchKernelGGL(mhist, dim3(RNB), dim3(256), 0, stream, ei, ghist, E);
    hipLaunchKernelGGL(scan1, dim3(snb), dim3(SCAN_B), 0, stream, ghist, gscan, bsumR, HTOT);
    hipLaunchKernelGGL(scan2, dim3(1), dim3(SCAN_B), 0, stream, bsumR, snb);
    hipLaunchKernelGGL(scan3g, dim3(snb), dim3(SCAN_B), 0, stream, gscan, bsumR, HTOT);
    hipLaunchKernelGGL(mscatter, dim3(RNB), dim3(256), 0, stream, ei, gscan, packed, E);
    hipLaunchKernelGGL(bucket_sort, dim3(RNB), dim3(256), 0, stream, packed, gscan, col, rp, E);

    // ---- casts ----
    hipLaunchKernelGGL(cast_f32_bf16, dim3(2048), dim3(256), 0, stream,
                       x, xb, N * 256 / 4);
    hipLaunchKernelGGL(build_bt, dim3(768), dim3(256), 0, stream,
                       W1l, W1r, W2l, W2r, Bt1, Bt2);

    // ---- layer 1: [y8|y2b] = xb@[W1l|W1r] (+b1); h = relu(mean(y8)+y2b) --
    hipLaunchKernelGGL((gemm_mfma<0>), dim3(4, mt), dim3(256), 0, stream,
                       xb, Bt1, b1, y8, y2b, (float*)nullptr, N);
    hipLaunchKernelGGL(fused_gather1, dim3((N + 3) / 4), dim3(256), 0, stream,
                       y8, y2b, rp, col, h, N);

    // ---- layer 2: [zb|out] = h@[W2l|W2r] (+b2 on out); out += mean(zb) ----
    hipLaunchKernelGGL((gemm_mfma<1>), dim3(2, mt), dim3(256), 0, stream,
                       h, Bt2, b2, (unsigned char*)nullptr, zb, out, N);
    hipLaunchKernelGGL(fused_gather2, dim3((N + 3) / 4), dim3(256), 0, stream,
                       zb, rp, col, out, N);
}